// Round 8
// baseline (61.749 us; speedup 1.0000x reference)
//
#include <hip/hip_runtime.h>
#include <stdint.h>

// Problem geometry (fixed by reference):
//   preds      [8, 21, 512, 512] f32
//   embeddings [8, 128, 128, 128] f32
//   gts        [8, 512, 512] i32  (unused)
//   fsss_gts   [8, 512, 512] i32
//   pos_memory [1000, 128] f32
//   neg_memory [1000, 128] f32
//   out: scalar f32
// Downsample 512->128 nearest picks rows/cols 4i, 4j exactly.
//
// Ledger of structural findings:
//  R3: cooperative grid.sync() ~60us/sync on MI355X (cross-XCD) -> banned.
//  R4: 4 dispatches, owner-block selection (ballot + redundant prefix) = 41us;
//      ~5-7us per dispatch boundary.
//  R6: single-finisher serial flag-walk = ~125us tail -> selection must stay
//      with owner blocks; completion-counter + CHEAP finisher (12KB dot) is ok.
//  R7: nontemporal loads on preds/fsss REGRESSED K1 by ~15us: they defeat the
//      cross-replay L3 residency (R6 counters showed FETCH=22.6MB vs 44MB
//      footprint = L3 serving half). Never NT-hint inputs under graph replay.
//  R8: R7 structure, plain loads.

#define NPOS  131072   // 8*128*128
#define NBLK  512      // NPOS / 256
#define MEMSZ 1000
#define KANC  100      // MEM/10
#define KPN   333      // MEM/3
#define SLOT_POS 100
#define SLOT_NEG 433
#define FIX_SCALE 1099511627776.0        // 2^40
#define INV_FIX   (1.0 / 1099511627776.0)

// ws byte layout
#define OFF_FLAGS   0          // 131072 B
#define OFF_COUNTS  131072     // 3*512*4 = 6144 B
#define OFF_IDX     137216     // 768*4   = 3072 B
#define OFF_TOTALS  140288     // 16 B
#define OFF_ACCUM   140304     // 4*3*128*8 = 12288 B (8-aligned)
#define OFF_CTR     152592     // 4 B

// ========= K1: argmax + masks + per-block counts; block 0 zeroes accum =========
__global__ __launch_bounds__(256) void mask_kernel(
    const float* __restrict__ preds,
    const int* __restrict__ fsss,
    uint8_t* __restrict__ flags,
    int* __restrict__ blockCounts,
    unsigned long long* __restrict__ accum,
    unsigned int* __restrict__ counterB)
{
    const int tid = threadIdx.x, blk = blockIdx.x;
    const int lane = tid & 63, wave = tid >> 6;
    const int n = blk * 256 + tid;
    const int b = n >> 14;
    const int ij = n & 16383;
    const int row = (ij >> 7) << 2;
    const int col = (ij & 127) << 2;

    const float* p = preds + (size_t)b * 21 * 262144 + (size_t)row * 512 + col;
    float best = p[0];
    int bc = 0;
#pragma unroll
    for (int c = 1; c < 21; ++c) {
        float v = p[(size_t)c * 262144];
        if (v > best) { best = v; bc = c; }   // strict > = first-max (jnp.argmax)
    }
    const int fv = fsss[(size_t)b * 262144 + (size_t)row * 512 + col];

    const bool pm = (bc != 0);
    const bool fm = (fv != 0) && (fv != 255);
    const int myflag = (int)(pm && fm)                // bit0: anchor
                     | ((int)(!pm && fm) << 1)        // bit1: positive
                     | ((int)(pm && (fv == 0)) << 2); // bit2: negative
    flags[n] = (uint8_t)myflag;

    __shared__ int s_i[12];
#pragma unroll
    for (int cat = 0; cat < 3; ++cat) {
        unsigned long long m = __ballot((myflag >> cat) & 1);
        if (lane == 0) s_i[cat * 4 + wave] = (int)__popcll(m);
    }
    __syncthreads();
    if (tid < 3)
        blockCounts[tid * NBLK + blk] =
            s_i[tid * 4] + s_i[tid * 4 + 1] + s_i[tid * 4 + 2] + s_i[tid * 4 + 3];

    // zero the fixed-point accumulators + K3's completion counter every call
    // (d_ws retains previous replay's values; K3 runs after K1 in stream order)
    if (blk == 0) {
        for (int i = tid; i < 4 * 3 * 128; i += 256) accum[i] = 0ull;
        if (tid == 0) *counterB = 0u;
    }
}

// ===== K2: per-block redundant prefix + owner-block first-k select (R4 pattern) =====
__global__ __launch_bounds__(256) void select_kernel(
    const uint8_t* __restrict__ flags,
    const int* __restrict__ blockCounts,
    int* __restrict__ idx,
    int* __restrict__ totals)
{
    const int tid = threadIdx.x, blk = blockIdx.x;
    const int lane = tid & 63, wave = tid >> 6;
    __shared__ int s_i[12];

    // --- sum of counts over blocks < blk (6KB table, L2/L3-resident) ---
#pragma unroll
    for (int cat = 0; cat < 3; ++cat) {
        const int c0 = blockCounts[cat * NBLK + tid];
        const int c1 = blockCounts[cat * NBLK + 256 + tid];
        int v = ((tid < blk) ? c0 : 0) + ((256 + tid < blk) ? c1 : 0);
#pragma unroll
        for (int off = 1; off < 64; off <<= 1) v += __shfl_xor(v, off, 64);
        if (lane == 0) s_i[cat * 4 + wave] = v;
    }
    __syncthreads();
    int pre[3];
#pragma unroll
    for (int cat = 0; cat < 3; ++cat)
        pre[cat] = s_i[cat * 4] + s_i[cat * 4 + 1] + s_i[cat * 4 + 2] + s_i[cat * 4 + 3];
    if (blk == NBLK - 1 && tid < 3)
        totals[tid] = pre[tid] + blockCounts[tid * NBLK + NBLK - 1];
    __syncthreads();   // s_i reuse below

    // --- first-k selection via ballots; O(1) rank per thread ---
    const int n = blk * 256 + tid;
    const int f = flags[n];
    unsigned long long masks[3];
#pragma unroll
    for (int cat = 0; cat < 3; ++cat) {
        masks[cat] = __ballot((f >> cat) & 1);
        if (lane == 0) s_i[cat * 4 + wave] = (int)__popcll(masks[cat]);
    }
    __syncthreads();
    const int kcap[3]  = {KANC, KPN, KPN};
    const int basec[3] = {0, SLOT_POS, SLOT_NEG};
#pragma unroll
    for (int cat = 0; cat < 3; ++cat) {
        if ((f >> cat) & 1) {
            int woff = 0;
#pragma unroll
            for (int w = 0; w < 4; ++w) if (w < wave) woff += s_i[cat * 4 + w];
            const int intra = woff + (int)__popcll(masks[cat] & ((1ull << lane) - 1ull));
            const int rank = pre[cat] + intra;
            if (rank < kcap[cat]) idx[basec[cat] + rank] = n;
        }
    }
}

// ====== K3: gather+normalize -> fixed-point accum; cheap finisher does the dot ======
// blocks 0..382: 2 slots each.  blocks 383..398: untouched-memory-row tails.
__global__ __launch_bounds__(256) void gather_final_kernel(
    const float* __restrict__ emb,
    const float* __restrict__ posMem,
    const float* __restrict__ negMem,
    const int* __restrict__ idx,
    const int* __restrict__ totals,
    unsigned long long* __restrict__ accum,   // [4 shadows][3 cats][128]
    unsigned int* __restrict__ counterB,
    float* __restrict__ out)
{
    const int tid = threadIdx.x, blk = blockIdx.x;
    const int lane = tid & 63, wave = tid >> 6;
    const int d = tid & 127;
    const int A = min(KANC, totals[0]);
    const int P = min(KPN, totals[1]);
    const int Q = min(KPN, totals[2]);

    if (blk < 383) {
        const int half = tid >> 7;
        const int slot = blk * 2 + half;      // 0..765
        int cat; bool valid;
        if (slot < SLOT_POS)      { cat = 0; valid = slot < A; }
        else if (slot < SLOT_NEG) { cat = 1; valid = (slot - SLOT_POS) < P; }
        else                      { cat = 2; valid = (slot - SLOT_NEG) < Q; }

        float v = 0.f;
        if (valid) {
            const int nn = idx[slot];
            v = emb[((size_t)(nn >> 14) * 128 + d) * 16384 + (nn & 16383)];
        }
        float sq = v * v;
#pragma unroll
        for (int off = 1; off < 64; off <<= 1) sq += __shfl_xor(sq, off, 64);
        __shared__ float s_f[4];
        if (lane == 0) s_f[wave] = sq;
        __syncthreads();
        const float nrm2 = s_f[half * 2] + s_f[half * 2 + 1];
        if (valid) {
            const float scale = 1.0f / fmaxf(sqrtf(nrm2), 1e-12f);
            const long long fx =
                (long long)llrint((double)v * (double)scale * FIX_SCALE);
            atomicAdd(&accum[(((blk & 3) * 3 + cat) << 7) + d],
                      (unsigned long long)fx);
        }
    } else {
        const int t = blk - 383;
        const int memSel = t >> 3;            // 0=pos, 1=neg
        const int part = t & 7;
        const float* mem = memSel ? negMem : posMem;
        const int cnt = memSel ? Q : P;       // rows [0,cnt) replaced by selections
        const int rowHalf = tid >> 7;
        const int m0 = part * 125;
        double acc = 0.0;
        for (int r = rowHalf; r < 125; r += 2) {
            const int m = m0 + r;
            if (m >= cnt) acc += (double)mem[(size_t)m * 128 + d];
        }
        const long long fx = (long long)llrint(acc * FIX_SCALE);
        atomicAdd(&accum[(((blk & 3) * 3 + (memSel ? 2 : 1)) << 7) + d],
                  (unsigned long long)fx);
    }

    // ---- release, completion count (cheap-finisher pattern, proven in R6-KB) ----
    __threadfence();
    __syncthreads();
    __shared__ int s_fin;
    if (tid == 0) {
        unsigned old = atomicAdd(counterB, 1u);
        s_fin = (old == 398) ? 1 : 0;
    }
    __syncthreads();
    if (!s_fin) return;
    __threadfence();

    // ---- finisher: final dot + relu (reads only 12KB accum) ----
    __shared__ double s_d[2];
    if (tid < 128) {
        double anc = 0.0, pos = 0.0, neg = 0.0;
#pragma unroll
        for (int s = 0; s < 4; ++s) {
            anc += (double)(long long)accum[((s * 3 + 0) << 7) + tid];
            pos += (double)(long long)accum[((s * 3 + 1) << 7) + tid];
            neg += (double)(long long)accum[((s * 3 + 2) << 7) + tid];
        }
        double prod = anc * (pos - neg) * (INV_FIX * INV_FIX);
#pragma unroll
        for (int off = 1; off < 64; off <<= 1) prod += __shfl_xor(prod, off, 64);
        if (lane == 0) s_d[wave] = prod;
    }
    __syncthreads();
    if (tid == 0) {
        const double red = s_d[0] + s_d[1];
        const double nAnc = (A > 0) ? (double)A : 1.0;
        const double vv = red / (nAnc * (double)MEMSZ) + 0.2;
        out[0] = (float)(vv > 0.0 ? vv : 0.0);
    }
}

extern "C" void kernel_launch(void* const* d_in, const int* in_sizes, int n_in,
                              void* d_out, int out_size, void* d_ws, size_t ws_size,
                              hipStream_t stream) {
    const float* preds  = (const float*)d_in[0];
    const float* emb    = (const float*)d_in[1];
    // d_in[2] = gts, unused by the loss
    const int* fsss     = (const int*)d_in[3];
    const float* posMem = (const float*)d_in[4];
    const float* negMem = (const float*)d_in[5];
    float* out = (float*)d_out;

    char* ws = (char*)d_ws;
    uint8_t* flags      = (uint8_t*)(ws + OFF_FLAGS);
    int* blockCounts    = (int*)(ws + OFF_COUNTS);
    int* idx            = (int*)(ws + OFF_IDX);
    int* totals         = (int*)(ws + OFF_TOTALS);
    unsigned long long* accum = (unsigned long long*)(ws + OFF_ACCUM);
    unsigned int* ctr   = (unsigned int*)(ws + OFF_CTR);

    mask_kernel  <<<NBLK, 256, 0, stream>>>(preds, fsss, flags, blockCounts,
                                            accum, ctr);
    select_kernel<<<NBLK, 256, 0, stream>>>(flags, blockCounts, idx, totals);
    gather_final_kernel<<<399, 256, 0, stream>>>(emb, posMem, negMem, idx, totals,
                                                 accum, ctr, out);
}